// Round 12
// baseline (996.447 us; speedup 1.0000x reference)
//
#include <hip/hip_runtime.h>
#include <math.h>

#define NN 8192
#define DIN 256
#define DOUT 128
#define HS 8208   // padded hT row stride (bf16 elems)

typedef __attribute__((ext_vector_type(8))) short short8;
typedef __attribute__((ext_vector_type(8))) __bf16 bf16x8;
typedef __attribute__((ext_vector_type(4))) float f32x4;
typedef __attribute__((ext_vector_type(4))) int int4v;
typedef __attribute__((ext_vector_type(4))) float float4v;
typedef __attribute__((ext_vector_type(4))) unsigned short ushort4v;

__device__ __forceinline__ bf16x8 as_bf(short8 s) { return __builtin_bit_cast(bf16x8, s); }
__device__ __forceinline__ unsigned short f2bf(float f) {
  union { float ff; unsigned int i; } v; v.ff = f;
  unsigned int r = v.i + 0x7FFFu + ((v.i >> 16) & 1u);
  return (unsigned short)(r >> 16);
}

// ---- Kernel 1: VERBATIM green R8 MFMA h-projection ---------------------------
__global__ __launch_bounds__(64) void k1_h(
    const float* __restrict__ feat, const float* __restrict__ W,
    const float* __restrict__ bias, const float* __restrict__ w1,
    const float* __restrict__ b1, const float* __restrict__ w2,
    const float* __restrict__ b2,
    float* __restrict__ h, unsigned short* __restrict__ hT,
    float* __restrict__ a1, float* __restrict__ a2)
{
  const int lane = threadIdx.x;
  const int m = lane & 15, q = lane >> 4;
  const int r0 = blockIdx.x * 16;

  f32x4 acc[8] = {};
  const float* fRow = feat + (size_t)(r0 + m) * DIN + q * 8;
#pragma unroll
  for (int k0 = 0; k0 < DIN; k0 += 32) {
    short8 af;
#pragma unroll
    for (int t = 0; t < 8; ++t) af[t] = (short)f2bf(fRow[k0 + t]);
#pragma unroll
    for (int g = 0; g < 8; ++g) {
      const float* wRow = W + (size_t)(g * 16 + m) * DIN + k0 + q * 8;
      short8 wf;
#pragma unroll
      for (int t = 0; t < 8; ++t) wf[t] = (short)f2bf(wRow[t]);
      acc[g] = __builtin_amdgcn_mfma_f32_16x16x32_bf16(as_bf(af), as_bf(wf), acc[g], 0, 0, 0);
    }
  }
  float s1[4] = {0.f, 0.f, 0.f, 0.f}, s2[4] = {0.f, 0.f, 0.f, 0.f};
#pragma unroll
  for (int g = 0; g < 8; ++g) {
    const int d = g * 16 + m;
    const float bv = bias[d];
    const float w1v = w1[d];
    const float w2v = w2[d];
    ushort4v st;
#pragma unroll
    for (int r = 0; r < 4; ++r) {
      float v = acc[g][r] + bv;
      h[(size_t)(r0 + q * 4 + r) * DOUT + d] = v;
      st[r] = f2bf(v);
      s1[r] += v * w1v;
      s2[r] += v * w2v;
    }
    *(ushort4v*)(hT + (size_t)d * HS + r0 + q * 4) = st;
  }
#pragma unroll
  for (int r = 0; r < 4; ++r) {
    s1[r] += __shfl_xor(s1[r], 1, 64); s2[r] += __shfl_xor(s2[r], 1, 64);
    s1[r] += __shfl_xor(s1[r], 2, 64); s2[r] += __shfl_xor(s2[r], 2, 64);
    s1[r] += __shfl_xor(s1[r], 4, 64); s2[r] += __shfl_xor(s2[r], 4, 64);
    s1[r] += __shfl_xor(s1[r], 8, 64); s2[r] += __shfl_xor(s2[r], 8, 64);
  }
  if (m == 0) {
    const float bb1 = b1[0], bb2 = b2[0];
#pragma unroll
    for (int r = 0; r < 4; ++r) {
      a1[r0 + q * 4 + r] = s1[r] + bb1;
      a2[r0 + q * 4 + r] = s2[r] + bb2;
    }
  }
}

// ---- Kernel 2 (green verbatim): M[i] = lrelu(a1[i] + max_j a2[j]) ------------
__global__ __launch_bounds__(256) void k2_m(const float* __restrict__ a1,
                                            const float* __restrict__ a2,
                                            float* __restrict__ M)
{
  __shared__ float red[256];
  const int t = threadIdx.x;
  float mx = -1e30f;
  for (int i = t; i < NN; i += 256) mx = fmaxf(mx, a2[i]);
  red[t] = mx;
  __syncthreads();
  for (int s = 128; s > 0; s >>= 1) {
    if (t < s) red[t] = fmaxf(red[t], red[t + s]);
    __syncthreads();
  }
  const float a2m = red[0];
  for (int i = t; i < NN; i += 256) {
    float y = a1[i] + a2m;
    M[i] = fmaxf(y, 0.01f * y);
  }
}

// ---- Kernel 3 (MFMA, SINGLE-WAVE = k1's exact execution context) -------------
// grid 512 x block 64. One wave owns 16 rows x all 8192 j. No cross-wave state.
__global__ __launch_bounds__(64) void GATLayer_46024869544127_kernel(
    const int* __restrict__ adj, const float* __restrict__ h,
    const float* __restrict__ a1, const float* __restrict__ a2,
    const float* __restrict__ M, float* __restrict__ out)
{
  __shared__ float zSh[16];
  const int lane = threadIdx.x;
  const int m = lane & 15, q = lane >> 4;
  const int r0 = blockIdx.x * 16;
  const int row = r0 + m;

  const float a1v = a1[row];
  const float Mv = M[row];
  const int* adjRow = adj + (size_t)row * NN;

  f32x4 acc[8] = {};
  float z = 0.f;

  for (int j0 = 0; j0 < NN; j0 += 32) {
    const int jb = j0 + q * 8;
    int4v A0 = *(const int4v*)(adjRow + jb);
    int4v A1 = *(const int4v*)(adjRow + jb + 4);
    float4v B0 = *(const float4v*)(a2 + jb);
    float4v B1 = *(const float4v*)(a2 + jb + 4);

    short8 pf;
#pragma unroll
    for (int t = 0; t < 4; ++t) {
      float y = a1v + B0[t];
      float ly = fmaxf(y, 0.01f * y);
      float e = expf(ly - Mv);                  // <= 1 provably
      float p = (A0[t] > 0) ? e : 0.0f;
      z += p;
      pf[t] = (short)f2bf(p);
    }
#pragma unroll
    for (int t = 0; t < 4; ++t) {
      float y = a1v + B1[t];
      float ly = fmaxf(y, 0.01f * y);
      float e = expf(ly - Mv);
      float p = (A1[t] > 0) ? e : 0.0f;
      z += p;
      pf[t + 4] = (short)f2bf(p);
    }
#pragma unroll
    for (int g = 0; g < 8; ++g) {
      // B[n=g*16+m][k=q*8+t] = h[jb+t][g*16+m] (k1's wf build pattern, f32 src)
      const float* hcol = h + (size_t)jb * DOUT + (g * 16 + m);
      short8 hb;
#pragma unroll
      for (int t = 0; t < 8; ++t) hb[t] = (short)f2bf(hcol[(size_t)t * DOUT]);
      acc[g] = __builtin_amdgcn_mfma_f32_16x16x32_bf16(as_bf(pf), as_bf(hb), acc[g], 0, 0, 0);
    }
  }

  // zz per attention-row m -> transpose to D-rows via tiny LDS
  z += __shfl_xor(z, 16, 64);
  z += __shfl_xor(z, 32, 64);
  if (lane < 16) zSh[m] = z;
  __syncthreads();

  // D layout (k1-validated): row = q*4+r, col = g*16+m; store = k1's h-store map
#pragma unroll
  for (int g = 0; g < 8; ++g) {
    const int d = g * 16 + m;
#pragma unroll
    for (int r = 0; r < 4; ++r) {
      const float zz = zSh[q * 4 + r];
      out[(size_t)(r0 + q * 4 + r) * DOUT + d] = (zz > 0.f) ? (acc[g][r] / zz) : 0.f;
    }
  }
}

extern "C" void kernel_launch(void* const* d_in, const int* in_sizes, int n_in,
                              void* d_out, int out_size, void* d_ws, size_t ws_size,
                              hipStream_t stream) {
  const float* feat = (const float*)d_in[0];
  const int* adj = (const int*)d_in[1];
  const float* W = (const float*)d_in[2];
  const float* b = (const float*)d_in[3];
  const float* w1 = (const float*)d_in[4];
  const float* b1 = (const float*)d_in[5];
  const float* w2 = (const float*)d_in[6];
  const float* b2 = (const float*)d_in[7];
  float* out = (float*)d_out;

  char* ws = (char*)d_ws;
  float* h = (float*)ws;                                               // 4 MB f32
  unsigned short* hT = (unsigned short*)(ws + (size_t)NN * DOUT * 4);  // ~2.1 MB bf16
  float* a1 = (float*)(ws + (size_t)NN * DOUT * 4 + (size_t)DOUT * HS * 2);
  float* a2 = a1 + NN;
  float* M  = a2 + NN;

  k1_h<<<512, 64, 0, stream>>>(feat, W, b, w1, b1, w2, b2, h, hT, a1, a2);
  k2_m<<<1, 256, 0, stream>>>(a1, a2, M);
  GATLayer_46024869544127_kernel<<<512, 64, 0, stream>>>(adj, h, a1, a2, M, out);
}